// Round 13
// baseline (18156.677 us; speedup 1.0000x reference)
//
#include <hip/hip_runtime.h>
#include <math.h>

#define VOC 32000
#define HID 512
#define BAT 32
#define SEQ 64

// ---- ws layout (BYTE offsets), all f32 unless noted ----
#define B_EIHT 0u          // [512][2048] enc Wih^T, gate-interleaved cols p=j*4+g
#define B_EHHT 4194304u    // [512][2048] enc Whh^T (interleaved)
#define B_DIHT 8388608u    // [512][2048] dec Wih^T (interleaved)
#define B_DHHT 12582912u   // [512][2048] dec Whh^T (interleaved)
#define B_E2   16777216u   // [2048][512] gathered enc embeddings
#define B_XD   20971520u   // [2048][2048] enc x-dots (interleaved p), r=b*64+t
#define B_H    37748736u   // [2][32][512] ping-pong h
#define B_C    37879808u   // [2][32][512]
#define B_LG   38010880u   // [32][32000] logits, then shifted
#define B_PM   42106880u   // [32][512] per-chunk partial max
#define B_TK   42172416u   // int [32] tokens
// total ~42.2 MB

// ---- d_out layout (f32 element offsets) ----
#define OUT_TOK  0u
#define OUT_LOGP 2048u
#define OUT_ENC  65538048u

__device__ __forceinline__ unsigned long long packkey(float x, int v) {
    unsigned int fb = __float_as_uint(x);
    unsigned int key = (fb & 0x80000000u) ? ~fb : (fb | 0x80000000u);
    return ((unsigned long long)key << 32) | (unsigned int)(~(unsigned int)v);
}
__device__ __forceinline__ float sigf(float x) { return 1.0f / (1.0f + expf(-x)); }

// ---- transpose + gate-interleave: src [2048][512] -> dst[k][p], p = (row&511)*4 | row>>9
__global__ void k_trg(const float* __restrict__ src, float* __restrict__ dst) {
    __shared__ float lds[32][33];
    int c0 = blockIdx.x * 32, r0 = blockIdx.y * 32;
    int cl = threadIdx.x & 31, r8 = threadIdx.x >> 5;
    for (int rr = 0; rr < 4; ++rr) {
        int r = r8 + rr * 8;
        lds[r][cl] = src[(size_t)(r0 + r) * HID + c0 + cl];
    }
    __syncthreads();
    for (int rr = 0; rr < 4; ++rr) {
        int idx = threadIdx.x + rr * 256;
        int rl = idx & 31, c2 = idx >> 5;
        int row = r0 + rl;
        int p = ((row & 511) << 2) | (row >> 9);
        dst[(size_t)(c0 + c2) * 2048 + p] = lds[rl][c2];
    }
}

// ---- gather enc input embeddings: E2[r][k] = emb[x[r]][k]
__global__ void k_gather(const int* __restrict__ x, const float* __restrict__ emb,
                         char* __restrict__ ws) {
    int r = blockIdx.x;
    const float* erow = emb + (size_t)x[r] * HID;
    float* e2 = (float*)(ws + B_E2) + (size_t)r * HID;
    e2[threadIdx.x] = erow[threadIdx.x];
    e2[threadIdx.x + 256] = erow[threadIdx.x + 256];
}

// ---- enc x-dots, 16-row register tile: XD[r][p] = fmaf-chain_k(EIHT[k][p] * E2[r][k])
__global__ void __launch_bounds__(256) k_xd2(char* __restrict__ ws) {
    int rt = blockIdx.x;          // 0..127
    int jc = blockIdx.y;          // 0..7
    int p = jc * 256 + threadIdx.x;
    const float* WT = (const float*)(ws + B_EIHT);
    const float* E2 = (const float*)(ws + B_E2) + (size_t)rt * 16 * HID;
    float acc[16];
#pragma unroll
    for (int i = 0; i < 16; ++i) acc[i] = 0.f;
    for (int k = 0; k < HID; ++k) {
        float w = WT[(size_t)k * 2048 + p];
#pragma unroll
        for (int rr = 0; rr < 16; ++rr)
            acc[rr] = fmaf(w, E2[rr * HID + k], acc[rr]);   // E2 uniform -> scalar loads
    }
    float* XD = (float*)(ws + B_XD);
#pragma unroll
    for (int rr = 0; rr < 16; ++rr)
        XD[(size_t)(rt * 16 + rr) * 2048 + p] = acc[rr];
}

// ---- zero parity-0 h,c
__global__ void k_zero(char* __restrict__ ws) {
    int i = blockIdx.x * 256 + threadIdx.x;   // 16384
    ((float*)(ws + B_H))[i] = 0.f;
    ((float*)(ws + B_C))[i] = 0.f;
}

// ---- fused gates+cell. grid 256: b=bid>>3, jc=bid&7; thread gate p=jc*256+tid
__global__ void __launch_bounds__(256) k_step(const float* __restrict__ bih,
                                              const float* __restrict__ bhh,
                                              const float* __restrict__ emb,
                                              const int* __restrict__ sos,
                                              const float* __restrict__ Hin,
                                              const float* __restrict__ Cin,
                                              float* __restrict__ Hout,
                                              float* __restrict__ Cout,
                                              char* __restrict__ ws,
                                              float* __restrict__ dout,
                                              int t, int mode) {
    __shared__ float e_s[512];
    __shared__ float gsh[256];
    int b = blockIdx.x >> 3, jc = blockIdx.x & 7;
    int p = jc * 256 + threadIdx.x;
    const float* hb = Hin + b * HID;
    float g;
    int oj = ((p & 3) << 9) | (p >> 2);       // original j4 = g*512 + j
    if (mode == 1) {
        int tok = (t == 0) ? sos[0] : ((const int*)(ws + B_TK))[b];
        const float* erow = emb + (size_t)tok * HID;
        e_s[threadIdx.x] = erow[threadIdx.x];
        e_s[threadIdx.x + 256] = erow[threadIdx.x + 256];
        __syncthreads();
        const float* WI = (const float*)(ws + B_DIHT);
        const float* WH = (const float*)(ws + B_DHHT);
        float aI = 0.f, aH = 0.f;
        for (int k = 0; k < HID; ++k) {        // two independent chains, each ascending k
            aI = fmaf(WI[(size_t)k * 2048 + p], e_s[k], aI);
            aH = fmaf(WH[(size_t)k * 2048 + p], hb[k], aH);
        }
        g = (aI + aH) + bih[oj];
        g = g + bhh[oj];
    } else {
        const float* WH = (const float*)(ws + B_EHHT);
        float aH = 0.f;
        for (int k = 0; k < HID; ++k)
            aH = fmaf(WH[(size_t)k * 2048 + p], hb[k], aH);
        float xd = ((const float*)(ws + B_XD))[(size_t)(b * SEQ + t) * 2048 + p];
        g = (xd + aH) + bih[oj];
        g = g + bhh[oj];
    }
    gsh[threadIdx.x] = g;
    __syncthreads();
    if (threadIdx.x < 64) {
        int j = jc * 64 + threadIdx.x;
        float gi = gsh[threadIdx.x * 4 + 0];
        float gf = gsh[threadIdx.x * 4 + 1];
        float gg = gsh[threadIdx.x * 4 + 2];
        float go = gsh[threadIdx.x * 4 + 3];
        float ip = sigf(gi), fp = sigf(gf), gp = tanhf(gg), op = sigf(go);
        // numpy-exact cell: mul, mul, add, mul — all f32 RN, no contraction
        float cn = __fadd_rn(__fmul_rn(fp, Cin[b * HID + j]), __fmul_rn(ip, gp));
        float hn = __fmul_rn(op, tanhf(cn));
        Hout[b * HID + j] = hn;
        Cout[b * HID + j] = cn;
        if (mode == 0)
            dout[OUT_ENC + (size_t)b * (SEQ * HID) + (size_t)t * HID + j] = hn;
    }
}

// ---- logits: grid (125,1), acc[32] — Wout read exactly once per step
__global__ void __launch_bounds__(256) k_logits(const float* __restrict__ Hin,
                                                const float* __restrict__ Wout,
                                                const float* __restrict__ bout,
                                                char* __restrict__ ws) {
    int vb = blockIdx.x;
    int v = vb * 256 + threadIdx.x;
    const float* wr = Wout + (size_t)v * HID;
    float acc[32];
#pragma unroll
    for (int i = 0; i < 32; ++i) acc[i] = 0.f;
    for (int k = 0; k < HID; k += 4) {
        float4 w = *(const float4*)&wr[k];
#pragma unroll
        for (int bb = 0; bb < 32; ++bb) {
            float4 h4 = *(const float4*)&Hin[(size_t)bb * HID + k];  // uniform -> scalar
            float a = acc[bb];
            a = fmaf(w.x, h4.x, a);           // strictly ascending k, single accumulator
            a = fmaf(w.y, h4.y, a);
            a = fmaf(w.z, h4.z, a);
            a = fmaf(w.w, h4.w, a);
            acc[bb] = a;
        }
    }
    float bq = bout[v];
    float* LG = (float*)(ws + B_LG);
    float mx[32];
#pragma unroll
    for (int bb = 0; bb < 32; ++bb) {
        float lg = acc[bb] + bq;
        LG[(size_t)bb * VOC + v] = lg;
        mx[bb] = lg;
    }
#pragma unroll
    for (int m = 1; m < 64; m <<= 1)
#pragma unroll
        for (int bb = 0; bb < 32; ++bb) mx[bb] = fmaxf(mx[bb], __shfl_xor(mx[bb], m));
    if ((threadIdx.x & 63) == 0) {
        int col = vb * 4 + (threadIdx.x >> 6);
#pragma unroll
        for (int bb = 0; bb < 32; ++bb)
            ((float*)(ws + B_PM))[bb * 512 + col] = mx[bb];
    }
}

// ---- fused softmax chain: max -> shift/exp/PS -> finS-replica lse -> logp+argmax+token
__global__ void __launch_bounds__(256) k_soft(char* __restrict__ ws, float* __restrict__ dout, int t) {
    __shared__ float ps_sh[512];
    __shared__ float msh[4], ssh[4];
    __shared__ unsigned long long pksh[4];
    int b = blockIdx.x;
    int tid = threadIdx.x, lane = tid & 63, wv = tid >> 6;
    // Phase 1: row max over PM (order-free fmax)
    const float* pm = (const float*)(ws + B_PM) + b * 512;
    float m = -3.4e38f;
    for (int c = tid; c < 500; c += 256) m = fmaxf(m, pm[c]);
#pragma unroll
    for (int k = 1; k < 64; k <<= 1) m = fmaxf(m, __shfl_xor(m, k));
    if (lane == 0) msh[wv] = m;
    __syncthreads();
    float M = fmaxf(fmaxf(msh[0], msh[1]), fmaxf(msh[2], msh[3]));
    // Phase 2: shifted + exp + per-64-chunk butterfly sums (bit-exact PS replica:
    // chunk c, lane l <-> v = c*64+l, identical shfl_xor pattern)
    float* lg = (float*)(ws + B_LG) + (size_t)b * VOC;
    for (int c = wv; c < 500; c += 4) {
        float sv = lg[c * 64 + lane] - M;
        lg[c * 64 + lane] = sv;
        float e = expf(sv);
#pragma unroll
        for (int k = 1; k < 64; k <<= 1) e += __shfl_xor(e, k);
        if (lane == 0) ps_sh[c] = e;
    }
    __syncthreads();
    // Phase 3: finS replica (strided chains + butterfly + 4-slot left-assoc + logf)
    float s = 0.f;
    for (int c = tid; c < 500; c += 256) s += ps_sh[c];
#pragma unroll
    for (int k = 1; k < 64; k <<= 1) s += __shfl_xor(s, k);
    if (lane == 0) ssh[wv] = s;
    __syncthreads();
    float L = logf(((ssh[0] + ssh[1]) + ssh[2]) + ssh[3]);
    // Phase 4: logp write + order-free u64 argmax + token
    float* outrow = dout + OUT_LOGP + (size_t)(b * SEQ + t) * VOC;
    unsigned long long pk = 0ull;
    for (int i = tid; i < VOC; i += 256) {
        float lp = lg[i] - L;
        outrow[i] = lp;
        unsigned long long o = packkey(lp, i);
        if (o > pk) pk = o;
    }
#pragma unroll
    for (int k = 1; k < 64; k <<= 1) {
        unsigned long long o = __shfl_xor(pk, k);
        if (o > pk) pk = o;
    }
    if (lane == 0) pksh[wv] = pk;
    __syncthreads();
    if (tid == 0) {
        pk = pksh[0];
        if (pksh[1] > pk) pk = pksh[1];
        if (pksh[2] > pk) pk = pksh[2];
        if (pksh[3] > pk) pk = pksh[3];
        int v = (int)(~(unsigned)(pk & 0xFFFFFFFFull));
        ((int*)(ws + B_TK))[b] = v;
        dout[OUT_TOK + b * SEQ + t] = (float)v;
    }
}

extern "C" void kernel_launch(void* const* d_in, const int* in_sizes, int n_in,
                              void* d_out, int out_size, void* d_ws, size_t ws_size,
                              hipStream_t stream) {
    const int*   x    = (const int*)d_in[0];
    const float* emb  = (const float*)d_in[1];
    const float* eWih = (const float*)d_in[2];
    const float* eWhh = (const float*)d_in[3];
    const float* ebih = (const float*)d_in[4];
    const float* ebhh = (const float*)d_in[5];
    const float* dWih = (const float*)d_in[6];
    const float* dWhh = (const float*)d_in[7];
    const float* dbih = (const float*)d_in[8];
    const float* dbhh = (const float*)d_in[9];
    const float* Wout = (const float*)d_in[10];
    const float* bout = (const float*)d_in[11];
    const int*   sos  = (const int*)d_in[12];
    float* out = (float*)d_out;
    char*  ws  = (char*)d_ws;

    float* H = (float*)(ws + B_H);   // parity stride 16384 floats
    float* C = (float*)(ws + B_C);

    hipLaunchKernelGGL(k_trg, dim3(16, 64), dim3(256), 0, stream, eWih, (float*)(ws + B_EIHT));
    hipLaunchKernelGGL(k_trg, dim3(16, 64), dim3(256), 0, stream, eWhh, (float*)(ws + B_EHHT));
    hipLaunchKernelGGL(k_trg, dim3(16, 64), dim3(256), 0, stream, dWih, (float*)(ws + B_DIHT));
    hipLaunchKernelGGL(k_trg, dim3(16, 64), dim3(256), 0, stream, dWhh, (float*)(ws + B_DHHT));
    hipLaunchKernelGGL(k_gather, dim3(2048), dim3(256), 0, stream, x, emb, ws);
    hipLaunchKernelGGL(k_xd2, dim3(128, 8), dim3(256), 0, stream, ws);
    hipLaunchKernelGGL(k_zero, dim3(64), dim3(256), 0, stream, ws);

    for (int t = 0; t < SEQ; ++t) {
        int pi = t & 1, po = pi ^ 1;
        hipLaunchKernelGGL(k_step, dim3(256), dim3(256), 0, stream,
                           ebih, ebhh, emb, sos, H + pi * 16384, C + pi * 16384,
                           H + po * 16384, C + po * 16384, ws, out, t, 0);
    }
    for (int t = 0; t < SEQ; ++t) {
        int pi = t & 1, po = pi ^ 1;
        hipLaunchKernelGGL(k_step, dim3(256), dim3(256), 0, stream,
                           dbih, dbhh, emb, sos, H + pi * 16384, C + pi * 16384,
                           H + po * 16384, C + po * 16384, ws, out, t, 1);
        hipLaunchKernelGGL(k_logits, dim3(125), dim3(256), 0, stream,
                           H + po * 16384, Wout, bout, ws);
        hipLaunchKernelGGL(k_soft, dim3(32), dim3(256), 0, stream, ws, out, t);
    }
}

// Round 14
// 14534.103 us; speedup vs baseline: 1.2492x; 1.2492x over previous
//
#include <hip/hip_runtime.h>
#include <math.h>

#define VOC 32000
#define HID 512
#define BAT 32
#define SEQ 64

// ---- ws layout (BYTE offsets), all f32 unless noted ----
#define B_EIHT 0u          // [512][2048] enc Wih^T, gate-interleaved cols p=j*4+g
#define B_EHHT 4194304u    // [512][2048] enc Whh^T (interleaved)
#define B_DIHT 8388608u    // [512][2048] dec Wih^T (interleaved)
#define B_DHHT 12582912u   // [512][2048] dec Whh^T (interleaved)
#define B_E2   16777216u   // [2048][512] gathered enc embeddings
#define B_XD   20971520u   // [2048][2048] enc x-dots (interleaved p), r=b*64+t
#define B_H    37748736u   // [2][32][512] ping-pong h (row-major, for k_logits)
#define B_C    37879808u   // [2][32][512]
#define B_HT   38010880u   // [2][512][32] ping-pong h^T (k-major, for k_step chains)
#define B_ET   38141952u   // [512][32]    dec input embedding, k-major
#define B_LG   38207488u   // [32][32000] logits, then shifted
#define B_PM   42303488u   // [32][512] per-chunk partial max
#define B_TK   42369024u   // int [32] tokens
// total ~42.4 MB

// ---- d_out layout (f32 element offsets) ----
#define OUT_TOK  0u
#define OUT_LOGP 2048u
#define OUT_ENC  65538048u

__device__ __forceinline__ unsigned long long packkey(float x, int v) {
    unsigned int fb = __float_as_uint(x);
    unsigned int key = (fb & 0x80000000u) ? ~fb : (fb | 0x80000000u);
    return ((unsigned long long)key << 32) | (unsigned int)(~(unsigned int)v);
}
__device__ __forceinline__ float sigf(float x) { return 1.0f / (1.0f + expf(-x)); }

// ---- transpose + gate-interleave: src [2048][512] -> dst[k][p], p = (row&511)*4 | row>>9
__global__ void k_trg(const float* __restrict__ src, float* __restrict__ dst) {
    __shared__ float lds[32][33];
    int c0 = blockIdx.x * 32, r0 = blockIdx.y * 32;
    int cl = threadIdx.x & 31, r8 = threadIdx.x >> 5;
    for (int rr = 0; rr < 4; ++rr) {
        int r = r8 + rr * 8;
        lds[r][cl] = src[(size_t)(r0 + r) * HID + c0 + cl];
    }
    __syncthreads();
    for (int rr = 0; rr < 4; ++rr) {
        int idx = threadIdx.x + rr * 256;
        int rl = idx & 31, c2 = idx >> 5;
        int row = r0 + rl;
        int p = ((row & 511) << 2) | (row >> 9);
        dst[(size_t)(c0 + c2) * 2048 + p] = lds[rl][c2];
    }
}

// ---- gather enc input embeddings: E2[r][k] = emb[x[r]][k]
__global__ void k_gather(const int* __restrict__ x, const float* __restrict__ emb,
                         char* __restrict__ ws) {
    int r = blockIdx.x;
    const float* erow = emb + (size_t)x[r] * HID;
    float* e2 = (float*)(ws + B_E2) + (size_t)r * HID;
    e2[threadIdx.x] = erow[threadIdx.x];
    e2[threadIdx.x + 256] = erow[threadIdx.x + 256];
}

// ---- enc x-dots, 16-row register tile: XD[r][p] = fmaf-chain_k(EIHT[k][p] * E2[r][k])
__global__ void __launch_bounds__(256) k_xd2(char* __restrict__ ws) {
    int rt = blockIdx.x;          // 0..127
    int jc = blockIdx.y;          // 0..7
    int p = jc * 256 + threadIdx.x;
    const float* WT = (const float*)(ws + B_EIHT);
    const float* E2 = (const float*)(ws + B_E2) + (size_t)rt * 16 * HID;
    float acc[16];
#pragma unroll
    for (int i = 0; i < 16; ++i) acc[i] = 0.f;
    for (int k = 0; k < HID; ++k) {
        float w = WT[(size_t)k * 2048 + p];
#pragma unroll
        for (int rr = 0; rr < 16; ++rr)
            acc[rr] = fmaf(w, E2[rr * HID + k], acc[rr]);   // E2 uniform -> scalar loads
    }
    float* XD = (float*)(ws + B_XD);
#pragma unroll
    for (int rr = 0; rr < 16; ++rr)
        XD[(size_t)(rt * 16 + rr) * 2048 + p] = acc[rr];
}

// ---- zero parity-0 h,c,hT; init eT with emb[sos]
__global__ void k_zero(const int* __restrict__ sos, const float* __restrict__ emb,
                       char* __restrict__ ws) {
    int i = blockIdx.x * 256 + threadIdx.x;   // 16384
    ((float*)(ws + B_H))[i] = 0.f;
    ((float*)(ws + B_C))[i] = 0.f;
    ((float*)(ws + B_HT))[i] = 0.f;
    ((float*)(ws + B_ET))[i] = emb[(size_t)sos[0] * HID + (i >> 5)];  // eT[k][b]
}

// ---- fused gates+cell, lanes=batches. grid 256: block owns p in [bid*8, bid*8+8)
// wave w covers p = bid*8 + w*2 + {0,1}; lane b = tid&31
__global__ void __launch_bounds__(256) k_step(const float* __restrict__ bih,
                                              const float* __restrict__ bhh,
                                              const float* __restrict__ HTin,
                                              const float* __restrict__ Cin,
                                              float* __restrict__ Hout,
                                              float* __restrict__ HTout,
                                              float* __restrict__ Cout,
                                              char* __restrict__ ws,
                                              float* __restrict__ dout,
                                              int t, int mode) {
    __shared__ float gsh[8][32];
    int tid = threadIdx.x;
    int b = tid & 31;
    int half = (tid >> 5) & 1;
    int w = tid >> 6;
    int p = blockIdx.x * 8 + w * 2 + half;
    int oj = ((p & 3) << 9) | (p >> 2);       // original j4 = gate*512 + j
    float g;
    if (mode == 1) {
        const float* WI = (const float*)(ws + B_DIHT);
        const float* WH = (const float*)(ws + B_DHHT);
        const float* ET = (const float*)(ws + B_ET);
        float aI = 0.f, aH = 0.f;
        for (int k = 0; k < HID; ++k) {        // two independent chains, each ascending k
            aI = fmaf(WI[(size_t)k * 2048 + p], ET[k * 32 + b], aI);
            aH = fmaf(WH[(size_t)k * 2048 + p], HTin[k * 32 + b], aH);
        }
        g = (aI + aH) + bih[oj];
        g = g + bhh[oj];
    } else {
        const float* WH = (const float*)(ws + B_EHHT);
        float aH = 0.f;
        for (int k = 0; k < HID; ++k)
            aH = fmaf(WH[(size_t)k * 2048 + p], HTin[k * 32 + b], aH);
        float xd = ((const float*)(ws + B_XD))[(size_t)(b * SEQ + t) * 2048 + p];
        g = (xd + aH) + bih[oj];
        g = g + bhh[oj];
    }
    gsh[w * 2 + half][b] = g;
    __syncthreads();
    if (tid < 64) {
        int b2 = tid & 31, jl = tid >> 5;
        int j = blockIdx.x * 2 + jl;
        float gi = gsh[jl * 4 + 0][b2];
        float gf = gsh[jl * 4 + 1][b2];
        float gg = gsh[jl * 4 + 2][b2];
        float go = gsh[jl * 4 + 3][b2];
        float ip = sigf(gi), fp = sigf(gf), gp = tanhf(gg), op = sigf(go);
        // numpy-exact cell: mul, mul, add, mul — all f32 RN, no contraction
        float cn = __fadd_rn(__fmul_rn(fp, Cin[b2 * HID + j]), __fmul_rn(ip, gp));
        float hn = __fmul_rn(op, tanhf(cn));
        Hout[b2 * HID + j] = hn;
        HTout[j * 32 + b2] = hn;
        Cout[b2 * HID + j] = cn;
        if (mode == 0)
            dout[OUT_ENC + (size_t)b2 * (SEQ * HID) + (size_t)t * HID + j] = hn;
    }
}

// ---- logits: grid (125,4), acc[8], h via wave-uniform global loads (R12-proven)
__global__ void __launch_bounds__(256) k_logits(const float* __restrict__ Hin,
                                                const float* __restrict__ Wout,
                                                const float* __restrict__ bout,
                                                char* __restrict__ ws) {
    int vb = blockIdx.x, bh = blockIdx.y;     // vb 0..124, bh 0..3
    int v = vb * 256 + threadIdx.x;
    const float* wr = Wout + (size_t)v * HID;
    float acc[8];
#pragma unroll
    for (int i = 0; i < 8; ++i) acc[i] = 0.f;
    for (int k = 0; k < HID; k += 4) {
        float4 w = *(const float4*)&wr[k];
#pragma unroll
        for (int bb = 0; bb < 8; ++bb) {
            float4 h4 = *(const float4*)&Hin[(size_t)(bh * 8 + bb) * HID + k];  // uniform
            float a = acc[bb];
            a = fmaf(w.x, h4.x, a);           // strictly ascending k, single accumulator
            a = fmaf(w.y, h4.y, a);
            a = fmaf(w.z, h4.z, a);
            a = fmaf(w.w, h4.w, a);
            acc[bb] = a;
        }
    }
    float bq = bout[v];
    float* LG = (float*)(ws + B_LG);
    float mx[8];
#pragma unroll
    for (int bb = 0; bb < 8; ++bb) {
        float lg = acc[bb] + bq;
        LG[(size_t)(bh * 8 + bb) * VOC + v] = lg;
        mx[bb] = lg;
    }
#pragma unroll
    for (int m = 1; m < 64; m <<= 1)
#pragma unroll
        for (int bb = 0; bb < 8; ++bb) mx[bb] = fmaxf(mx[bb], __shfl_xor(mx[bb], m));
    if ((threadIdx.x & 63) == 0) {
        int col = vb * 4 + (threadIdx.x >> 6);
#pragma unroll
        for (int bb = 0; bb < 8; ++bb)
            ((float*)(ws + B_PM))[(bh * 8 + bb) * 512 + col] = mx[bb];
    }
}

// ---- fused softmax chain + eT gather for next step
__global__ void __launch_bounds__(256) k_soft(char* __restrict__ ws, float* __restrict__ dout,
                                              const float* __restrict__ emb, int t) {
    __shared__ float ps_sh[512];
    __shared__ float msh[4], ssh[4];
    __shared__ unsigned long long pksh[4];
    __shared__ int tokS;
    int b = blockIdx.x;
    int tid = threadIdx.x, lane = tid & 63, wv = tid >> 6;
    // Phase 1: row max over PM (order-free fmax)
    const float* pm = (const float*)(ws + B_PM) + b * 512;
    float m = -3.4e38f;
    for (int c = tid; c < 500; c += 256) m = fmaxf(m, pm[c]);
#pragma unroll
    for (int k = 1; k < 64; k <<= 1) m = fmaxf(m, __shfl_xor(m, k));
    if (lane == 0) msh[wv] = m;
    __syncthreads();
    float M = fmaxf(fmaxf(msh[0], msh[1]), fmaxf(msh[2], msh[3]));
    // Phase 2: shifted + exp + per-64-chunk butterfly sums
    float* lg = (float*)(ws + B_LG) + (size_t)b * VOC;
    for (int c = wv; c < 500; c += 4) {
        float sv = lg[c * 64 + lane] - M;
        lg[c * 64 + lane] = sv;
        float e = expf(sv);
#pragma unroll
        for (int k = 1; k < 64; k <<= 1) e += __shfl_xor(e, k);
        if (lane == 0) ps_sh[c] = e;
    }
    __syncthreads();
    // Phase 3: finS replica (strided chains + butterfly + 4-slot left-assoc + logf)
    float s = 0.f;
    for (int c = tid; c < 500; c += 256) s += ps_sh[c];
#pragma unroll
    for (int k = 1; k < 64; k <<= 1) s += __shfl_xor(s, k);
    if (lane == 0) ssh[wv] = s;
    __syncthreads();
    float L = logf(((ssh[0] + ssh[1]) + ssh[2]) + ssh[3]);
    // Phase 4: logp write + order-free u64 argmax + token
    float* outrow = dout + OUT_LOGP + (size_t)(b * SEQ + t) * VOC;
    unsigned long long pk = 0ull;
    for (int i = tid; i < VOC; i += 256) {
        float lp = lg[i] - L;
        outrow[i] = lp;
        unsigned long long o = packkey(lp, i);
        if (o > pk) pk = o;
    }
#pragma unroll
    for (int k = 1; k < 64; k <<= 1) {
        unsigned long long o = __shfl_xor(pk, k);
        if (o > pk) pk = o;
    }
    if (lane == 0) pksh[wv] = pk;
    __syncthreads();
    if (tid == 0) {
        pk = pksh[0];
        if (pksh[1] > pk) pk = pksh[1];
        if (pksh[2] > pk) pk = pksh[2];
        if (pksh[3] > pk) pk = pksh[3];
        int v = (int)(~(unsigned)(pk & 0xFFFFFFFFull));
        ((int*)(ws + B_TK))[b] = v;
        dout[OUT_TOK + b * SEQ + t] = (float)v;
        tokS = v;
    }
    __syncthreads();
    // Phase 5: gather next-step input embedding (k-major): eT[k][b] = emb[tok][k]
    int tok = tokS;
    const float* erow = emb + (size_t)tok * HID;
    float* ET = (float*)(ws + B_ET);
    for (int k = tid; k < HID; k += 256)
        ET[k * 32 + b] = erow[k];
}

extern "C" void kernel_launch(void* const* d_in, const int* in_sizes, int n_in,
                              void* d_out, int out_size, void* d_ws, size_t ws_size,
                              hipStream_t stream) {
    const int*   x    = (const int*)d_in[0];
    const float* emb  = (const float*)d_in[1];
    const float* eWih = (const float*)d_in[2];
    const float* eWhh = (const float*)d_in[3];
    const float* ebih = (const float*)d_in[4];
    const float* ebhh = (const float*)d_in[5];
    const float* dWih = (const float*)d_in[6];
    const float* dWhh = (const float*)d_in[7];
    const float* dbih = (const float*)d_in[8];
    const float* dbhh = (const float*)d_in[9];
    const float* Wout = (const float*)d_in[10];
    const float* bout = (const float*)d_in[11];
    const int*   sos  = (const int*)d_in[12];
    float* out = (float*)d_out;
    char*  ws  = (char*)d_ws;

    float* H  = (float*)(ws + B_H);    // parity stride 16384 floats
    float* C  = (float*)(ws + B_C);
    float* HT = (float*)(ws + B_HT);

    hipLaunchKernelGGL(k_trg, dim3(16, 64), dim3(256), 0, stream, eWih, (float*)(ws + B_EIHT));
    hipLaunchKernelGGL(k_trg, dim3(16, 64), dim3(256), 0, stream, eWhh, (float*)(ws + B_EHHT));
    hipLaunchKernelGGL(k_trg, dim3(16, 64), dim3(256), 0, stream, dWih, (float*)(ws + B_DIHT));
    hipLaunchKernelGGL(k_trg, dim3(16, 64), dim3(256), 0, stream, dWhh, (float*)(ws + B_DHHT));
    hipLaunchKernelGGL(k_gather, dim3(2048), dim3(256), 0, stream, x, emb, ws);
    hipLaunchKernelGGL(k_xd2, dim3(128, 8), dim3(256), 0, stream, ws);
    hipLaunchKernelGGL(k_zero, dim3(64), dim3(256), 0, stream, sos, emb, ws);

    for (int t = 0; t < SEQ; ++t) {
        int pi = t & 1, po = pi ^ 1;
        hipLaunchKernelGGL(k_step, dim3(256), dim3(256), 0, stream,
                           ebih, ebhh, HT + pi * 16384, C + pi * 16384,
                           H + po * 16384, HT + po * 16384, C + po * 16384,
                           ws, out, t, 0);
    }
    for (int t = 0; t < SEQ; ++t) {
        int pi = t & 1, po = pi ^ 1;
        hipLaunchKernelGGL(k_step, dim3(256), dim3(256), 0, stream,
                           dbih, dbhh, HT + pi * 16384, C + pi * 16384,
                           H + po * 16384, HT + po * 16384, C + po * 16384,
                           ws, out, t, 1);
        hipLaunchKernelGGL(k_logits, dim3(125, 4), dim3(256), 0, stream,
                           H + po * 16384, Wout, bout, ws);
        hipLaunchKernelGGL(k_soft, dim3(32), dim3(256), 0, stream, ws, out, emb, t);
    }
}